// Round 16
// baseline (249.766 us; speedup 1.0000x reference)
//
#include <hip/hip_runtime.h>

#define N_NODES 50000
#define N_EDGES 800000
#define DIM 128
#define WT_BLOCKS 192              // 3 * 128*128 / 256
#define GEMM_BLOCKS ((N_NODES + 63) / 64)   // 782 blocks: ~3/CU, small tail
#define NBUCKET ((N_NODES + 255) / 256)   // 196 buckets of 256 nodes (bucket = dst>>8)
#define P1_BLOCKS 200
#define P1_CHUNK 4000              // P1_BLOCKS * P1_CHUNK == N_EDGES
#define P2_BLOCKS 200
#define P2_CHUNK 4000
#define AGG_BLOCKS (N_NODES / 8)   // aggemm: 8 nodes/block, 512 thr

typedef unsigned int u32;
typedef short bf16x8 __attribute__((ext_vector_type(8)));
typedef float f32x4 __attribute__((ext_vector_type(4)));

static inline size_t alignUp(size_t x) { return (x + 255) & ~size_t(255); }

// fp32 -> bf16 round-to-nearest-even (finite values)
__device__ inline unsigned short f2bf(float f) {
    union { float f; u32 u; } v; v.f = f;
    u32 r = v.u + 0x7fffu + ((v.u >> 16) & 1u);
    return (unsigned short)(r >> 16);
}
__device__ inline float bf_lo(u32 u) { return __uint_as_float(u << 16); }
__device__ inline float bf_hi(u32 u) { return __uint_as_float(u & 0xffff0000u); }

__device__ inline void accum8(float acc[8], uint4 r, float w) {
    acc[0] += w * bf_lo(r.x); acc[1] += w * bf_hi(r.x);
    acc[2] += w * bf_lo(r.y); acc[3] += w * bf_hi(r.y);
    acc[4] += w * bf_lo(r.z); acc[5] += w * bf_hi(r.z);
    acc[6] += w * bf_lo(r.w); acc[7] += w * bf_hi(r.w);
}

// ---------------- prep: W->bf16 transpose (blocks [0,WT_BLOCKS)) + bucket counts ----------------
__global__ __launch_bounds__(256) void prep_kernel(const float* __restrict__ W1,
                                                   const float* __restrict__ W2,
                                                   const float* __restrict__ W3,
                                                   unsigned short* __restrict__ Wt,
                                                   const int* __restrict__ dst,
                                                   u32* __restrict__ bcnt) {
    __shared__ u32 hist[NBUCKET];
    int bid = blockIdx.x;
    if (bid < WT_BLOCKS) {
        int m = bid >> 6;                       // which matrix
        int e = (bid & 63) * 256 + threadIdx.x; // element within 128x128
        int n = e >> 7, k = e & 127;
        const float* W = (m == 0) ? W1 : (m == 1) ? W2 : W3;
        Wt[m * DIM * DIM + n * DIM + k] = f2bf(W[(size_t)k * DIM + n]);
        return;
    }
    int b = bid - WT_BLOCKS;
    for (int k = threadIdx.x; k < NBUCKET; k += 256) hist[k] = 0;
    __syncthreads();
    int e0 = b * P1_CHUNK;
    int e1 = min(e0 + P1_CHUNK, N_EDGES);
    for (int i = e0 + threadIdx.x; i < e1; i += 256)
        atomicAdd(&hist[((u32)dst[i]) >> 8], 1u);
    __syncthreads();
    for (int k = threadIdx.x; k < NBUCKET; k += 256)
        if (hist[k]) atomicAdd(&bcnt[k], hist[k]);
}

// ---------------- part: partition edges into bucket-major epart (packed src|dst<<16) ----------
// Bucket bases recomputed locally; bcur is a zero-based reservation counter.
__global__ __launch_bounds__(256) void part_kernel(const int* __restrict__ src,
                                                   const int* __restrict__ dst,
                                                   const u32* __restrict__ bcnt,
                                                   u32* __restrict__ bcur,
                                                   u32* __restrict__ epart) {
    __shared__ u32 ed[P2_CHUNK];
    __shared__ u32 hist[NBUCKET];
    __shared__ u32 cb[NBUCKET];
    __shared__ u32 rk[NBUCKET];
    __shared__ u32 bb[256];
    __shared__ u32 wsum[4];
    int tid = threadIdx.x, lane = tid & 63, wv = tid >> 6;
    u32 c = (tid < NBUCKET) ? bcnt[tid] : 0;
    u32 v = c;
#pragma unroll
    for (int off = 1; off < 64; off <<= 1) {
        u32 u = __shfl_up(v, off, 64);
        if (lane >= off) v += u;
    }
    if (lane == 63) wsum[wv] = v;
    for (int k = tid; k < NBUCKET; k += 256) { hist[k] = 0; rk[k] = 0; }
    __syncthreads();
    u32 wo = 0;
    for (int w = 0; w < wv; w++) wo += wsum[w];
    bb[tid] = wo + v - c;
    __syncthreads();
    int e0 = blockIdx.x * P2_CHUNK;
    int e1 = min(e0 + P2_CHUNK, N_EDGES);
    for (int i = e0 + tid; i < e1; i += 256) {
        u32 s = (u32)src[i], d = (u32)dst[i];
        u32 val = s | (d << 16);
        ed[i - e0] = val;
        atomicAdd(&hist[d >> 8], 1u);
    }
    __syncthreads();
    for (int k = tid; k < NBUCKET; k += 256) {
        u32 ck = hist[k];
        cb[k] = ck ? (bb[k] + atomicAdd(&bcur[k], ck)) : 0u;
    }
    __syncthreads();
    int n = e1 - e0;
    for (int k = tid; k < n; k += 256) {
        u32 val = ed[k];
        u32 bk = val >> 24;                 // (dst>>8), dst fits 16 bits
        u32 r = atomicAdd(&rk[bk], 1u);     // LDS rank
        epart[cb[bk] + r] = val;
    }
}

// ---------------- K1: MFMA GEMM h1 = x(fp32->bf16) @ W1t^T, + bucket-CSR build ----------
#define LDSTRIDE 40
__global__ __launch_bounds__(256) void gemm_mfma_kernel(const float* __restrict__ x,
                                                        const unsigned short* __restrict__ Wt,
                                                        unsigned short* __restrict__ hb,
                                                        int n_rows,
                                                        const u32* __restrict__ bcnt,
                                                        const u32* __restrict__ epart,
                                                        int* __restrict__ cnt,
                                                        int* __restrict__ base,
                                                        float* __restrict__ dinv,
                                                        unsigned short* __restrict__ csr16) {
    __shared__ unsigned short As[64 * LDSTRIDE];
    __shared__ unsigned short Bs[128 * LDSTRIDE];
    if (blockIdx.x >= GEMM_BLOCKS) {
        int B = blockIdx.x - GEMM_BLOCKS;   // bucket id
        u32* hcnt = (u32*)&As[0];           // 256 u32
        u32* pref = hcnt + 256;             // 256 u32
        u32* bbl  = pref + 256;             // 256 u32 (bucket-base scan)
        u32* wsum = bbl + 256;              // 4 u32
        int tid = threadIdx.x, lane = tid & 63, wv = tid >> 6;
        int nb0 = B << 8;
        u32 cb_ = (tid < NBUCKET) ? bcnt[tid] : 0;
        u32 vb = cb_;
#pragma unroll
        for (int off = 1; off < 64; off <<= 1) {
            u32 u = __shfl_up(vb, off, 64);
            if (lane >= off) vb += u;
        }
        if (lane == 63) wsum[wv] = vb;
        hcnt[tid] = 0;
        __syncthreads();
        u32 wob = 0;
        for (int w = 0; w < wv; w++) wob += wsum[w];
        bbl[tid] = wob + vb - cb_;
        __syncthreads();
        u32 ebeg = bbl[B];
        u32 esz  = bcnt[B];
        for (u32 k = tid; k < esz; k += 256)
            atomicAdd(&hcnt[(epart[ebeg + k] >> 16) & 255u], 1u);
        __syncthreads();
        u32 c = hcnt[tid];
        u32 v = c;
#pragma unroll
        for (int off = 1; off < 64; off <<= 1) {
            u32 u = __shfl_up(v, off, 64);
            if (lane >= off) v += u;
        }
        if (lane == 63) wsum[wv] = v;
        __syncthreads();
        u32 wo = 0;
        for (int w = 0; w < wv; w++) wo += wsum[w];
        u32 excl = wo + v - c;
        int node = nb0 + tid;
        if (node < N_NODES) {
            cnt[node]  = (int)c;
            base[node] = (int)(ebeg + excl);
            dinv[node] = rsqrtf((float)(c + 1));
        }
        pref[tid] = excl;
        __syncthreads();
        for (u32 k = tid; k < esz; k += 256) {
            u32 v2 = epart[ebeg + k];
            u32 dl = (v2 >> 16) & 255u;
            u32 r = atomicAdd(&pref[dl], 1u);
            csr16[ebeg + r] = (unsigned short)(v2 & 0xffffu);
        }
        return;
    }
    const int tid = threadIdx.x;
    const int wave = tid >> 6;
    const int lane = tid & 63;
    const int quad = lane >> 4;
    const int l16 = lane & 15;
    const int row0 = blockIdx.x * 64;

    f32x4 acc[8];
#pragma unroll
    for (int nt = 0; nt < 8; nt++) acc[nt] = (f32x4){0.f, 0.f, 0.f, 0.f};

    for (int k0 = 0; k0 < DIM; k0 += 32) {
        {
            int r = tid >> 2;
            int kq = (tid & 3) * 8;
            int gr = row0 + r;
            float4 v0 = make_float4(0.f, 0.f, 0.f, 0.f);
            float4 v1 = make_float4(0.f, 0.f, 0.f, 0.f);
            if (gr < n_rows) {
                v0 = *(const float4*)&x[(size_t)gr * DIM + k0 + kq];
                v1 = *(const float4*)&x[(size_t)gr * DIM + k0 + kq + 4];
            }
            u32 p0 = (u32)f2bf(v0.x) | ((u32)f2bf(v0.y) << 16);
            u32 p1 = (u32)f2bf(v0.z) | ((u32)f2bf(v0.w) << 16);
            u32 p2 = (u32)f2bf(v1.x) | ((u32)f2bf(v1.y) << 16);
            u32 p3 = (u32)f2bf(v1.z) | ((u32)f2bf(v1.w) << 16);
            *(uint4*)&As[r * LDSTRIDE + kq] = make_uint4(p0, p1, p2, p3);
        }
#pragma unroll
        for (int p = 0; p < 2; p++) {
            int nn = p * 64 + (tid >> 2);
            int kk = (tid & 3) * 8;
            *(uint4*)&Bs[nn * LDSTRIDE + kk] = *(const uint4*)&Wt[nn * DIM + k0 + kk];
        }
        __syncthreads();
        const int m0 = wave * 16;
        bf16x8 a = *(const bf16x8*)&As[(m0 + l16) * LDSTRIDE + quad * 8];
#pragma unroll
        for (int nt = 0; nt < 8; nt++) {
            bf16x8 b = *(const bf16x8*)&Bs[(nt * 16 + l16) * LDSTRIDE + quad * 8];
            acc[nt] = __builtin_amdgcn_mfma_f32_16x16x32_bf16(a, b, acc[nt], 0, 0, 0);
        }
        __syncthreads();
    }
    const int m0 = wave * 16;
#pragma unroll
    for (int reg = 0; reg < 4; reg++) {
        int gr = row0 + m0 + quad * 4 + reg;
        if (gr < n_rows) {
#pragma unroll
            for (int nt = 0; nt < 8; nt++)
                hb[(size_t)gr * DIM + nt * 16 + l16] = f2bf(acc[nt][reg]);
        }
    }
}

// ---------------- aggemm: agg(layer i) + GEMM(layer i+1) -----------------------
// Round-11 structure (LDS-staged W, no launch_bounds clamp) with the gather loop
// deepened 2 -> 4 (K4's uniform 16-edge loop). Rationale: counters show latency-
// bound (VALUBusy 48%, nothing saturated); 2-deep keeps only ~2.9 MB in flight
// device-wide. 4-deep doubles MLP. VGPR headroom exists (28 used / 64 budget);
// spill tripwire = WRITE_SIZE must stay ~12.5 MB (round-9 lesson).
#define FSTR 136   // 272-B rows: 16-B aligned; 2-way bank alias only (free)
__global__ __launch_bounds__(512) void aggemm_kernel(
        const uint4* __restrict__ hb_in,
        const unsigned short* __restrict__ Wt,      // NEXT layer's W^T (bf16)
        const int* __restrict__ cnt,
        const int* __restrict__ basep,
        const unsigned short* __restrict__ csr16,
        const float* __restrict__ dinv,
        const float4* __restrict__ bias4,           // CURRENT layer's bias
        unsigned short* __restrict__ hb_out) {
    __shared__ unsigned short As[16 * FSTR];
    __shared__ unsigned short Bs[128 * FSTR];
    const int tid = threadIdx.x;
    const int wave = tid >> 6;
    const int lane = tid & 63;
    const int g = lane >> 4;
    const int l16 = lane & 15;

    // stage full W (128x128 bf16): 2048 uint4, 4 per thread — issued first;
    // the ds_write+barrier structure pins these loads EARLY (under gather latency).
#pragma unroll
    for (int i = 0; i < 4; i++) {
        int idx = i * 512 + tid;
        int n = idx >> 4, k8 = (idx & 15) * 8;
        *(uint4*)&Bs[n * FSTR + k8] = *(const uint4*)&Wt[n * DIM + k8];
    }
    // zero As rows 8..15 (read by MFMA; outputs of those rows never stored)
    {
        u32* az = (u32*)As;
        for (int i = tid; i < (8 * FSTR) / 2; i += 512) az[(8 * FSTR) / 2 + i] = 0;
    }

    // -------- phase A: aggregate node = blk*8 + wave (identical to agg_kernel) ----
    const int node = blockIdx.x * 8 + wave;
    const int deg = cnt[node];
    const float di = dinv[node];
    const int start = basep[node];

    float acc[8];
#pragma unroll
    for (int i = 0; i < 8; i++) acc[i] = 0.f;

    for (int b0 = 0; b0 < deg; b0 += 64) {
        int m = min(64, deg - b0);
        int e = 0; float w = 0.f;
        if (lane < m) {
            e = csr16[start + b0 + lane];
            w = dinv[e];
        }
        for (int j4 = 0; j4 < m; j4 += 16) {   // 4-deep: 4 gathers in flight/lane-group
            int j0 = j4 + g, j1 = j4 + 4 + g, j2 = j4 + 8 + g, j3 = j4 + 12 + g;
            int s0 = __shfl(e, j0, 64);  float w0 = __shfl(w, j0, 64);
            int s1 = __shfl(e, j1, 64);  float w1 = __shfl(w, j1, 64);
            int s2 = __shfl(e, j2, 64);  float w2 = __shfl(w, j2, 64);
            int s3 = __shfl(e, j3, 64);  float w3 = __shfl(w, j3, 64);
            uint4 r0 = hb_in[(size_t)s0 * 16 + l16];
            uint4 r1 = hb_in[(size_t)s1 * 16 + l16];
            uint4 r2 = hb_in[(size_t)s2 * 16 + l16];
            uint4 r3 = hb_in[(size_t)s3 * 16 + l16];
            accum8(acc, r0, w0);
            accum8(acc, r1, w1);
            accum8(acc, r2, w2);
            accum8(acc, r3, w3);
        }
    }
    if (g == 0) {   // self-loop (inner weight = dinv[node])
        uint4 r = hb_in[(size_t)node * 16 + l16];
        accum8(acc, r, di);
    }
#pragma unroll
    for (int i = 0; i < 8; i++) {
        acc[i] += __shfl_xor(acc[i], 16, 64);
        acc[i] += __shfl_xor(acc[i], 32, 64);
    }
    if (g == 0) {
        float4 bv0 = bias4[l16 * 2], bv1 = bias4[l16 * 2 + 1];
        float res[8];
        res[0] = di * acc[0] + bv0.x; res[1] = di * acc[1] + bv0.y;
        res[2] = di * acc[2] + bv0.z; res[3] = di * acc[3] + bv0.w;
        res[4] = di * acc[4] + bv1.x; res[5] = di * acc[5] + bv1.y;
        res[6] = di * acc[6] + bv1.z; res[7] = di * acc[7] + bv1.w;
#pragma unroll
        for (int i = 0; i < 8; i++) res[i] = fmaxf(res[i], 0.f);   // fused layers: relu
        u32 p0 = (u32)f2bf(res[0]) | ((u32)f2bf(res[1]) << 16);
        u32 p1 = (u32)f2bf(res[2]) | ((u32)f2bf(res[3]) << 16);
        u32 p2 = (u32)f2bf(res[4]) | ((u32)f2bf(res[5]) << 16);
        u32 p3 = (u32)f2bf(res[6]) | ((u32)f2bf(res[7]) << 16);
        *(uint4*)&As[wave * FSTR + l16 * 8] = make_uint4(p0, p1, p2, p3);
    }
    __syncthreads();

    // -------- phase B: 8x128 @ 128x128 GEMM; wave = N-tile, K=128 in 4 MFMA ----
    const int nt = wave;
    f32x4 gacc = (f32x4){0.f, 0.f, 0.f, 0.f};
#pragma unroll
    for (int ks = 0; ks < 4; ks++) {
        bf16x8 a = *(const bf16x8*)&As[l16 * FSTR + ks * 32 + g * 8];
        bf16x8 b = *(const bf16x8*)&Bs[(nt * 16 + l16) * FSTR + ks * 32 + g * 8];
        gacc = __builtin_amdgcn_mfma_f32_16x16x32_bf16(a, b, gacc, 0, 0, 0);
    }
#pragma unroll
    for (int reg = 0; reg < 4; reg++) {
        int row = g * 4 + reg;          // C layout: row = quad*4+reg, col = l16
        if (row < 8) {
            int gr = blockIdx.x * 8 + row;
            hb_out[(size_t)gr * DIM + nt * 16 + l16] = f2bf(gacc[reg]);
        }
    }
}

// ---------------- final aggregation -> fp32 out ----------------
__global__ __launch_bounds__(256) void agg_kernel(const uint4* __restrict__ hb,
                                                  const int* __restrict__ cnt,
                                                  const int* __restrict__ basep,
                                                  const unsigned short* __restrict__ csr16,
                                                  const float* __restrict__ dinv,
                                                  const float4* __restrict__ bias4,
                                                  float* __restrict__ out) {
    const int wave = threadIdx.x >> 6;
    const int lane = threadIdx.x & 63;
    const int node = blockIdx.x * 4 + wave;
    const int g = lane >> 4;
    const int l16 = lane & 15;

    const int deg = cnt[node];
    const float di = dinv[node];
    const int start = basep[node];

    float acc[8];
#pragma unroll
    for (int i = 0; i < 8; i++) acc[i] = 0.f;

    for (int b0 = 0; b0 < deg; b0 += 64) {
        int m = min(64, deg - b0);
        int e = 0; float w = 0.f;
        if (lane < m) {
            e = csr16[start + b0 + lane];
            w = dinv[e];
        }
        for (int j4 = 0; j4 < m; j4 += 16) {
            int j0 = j4 + g, j1 = j4 + 4 + g, j2 = j4 + 8 + g, j3 = j4 + 12 + g;
            int s0 = __shfl(e, j0, 64);  float w0 = __shfl(w, j0, 64);
            int s1 = __shfl(e, j1, 64);  float w1 = __shfl(w, j1, 64);
            int s2 = __shfl(e, j2, 64);  float w2 = __shfl(w, j2, 64);
            int s3 = __shfl(e, j3, 64);  float w3 = __shfl(w, j3, 64);
            uint4 r0 = hb[(size_t)s0 * 16 + l16];
            uint4 r1 = hb[(size_t)s1 * 16 + l16];
            uint4 r2 = hb[(size_t)s2 * 16 + l16];
            uint4 r3 = hb[(size_t)s3 * 16 + l16];
            accum8(acc, r0, w0);
            accum8(acc, r1, w1);
            accum8(acc, r2, w2);
            accum8(acc, r3, w3);
        }
    }
    if (g == 0) {
        uint4 r = hb[(size_t)node * 16 + l16];
        accum8(acc, r, di);
    }
#pragma unroll
    for (int i = 0; i < 8; i++) {
        acc[i] += __shfl_xor(acc[i], 16, 64);
        acc[i] += __shfl_xor(acc[i], 32, 64);
    }
    if (g == 0) {
        float4 b0 = bias4[l16 * 2], b1 = bias4[l16 * 2 + 1];
        float4* o = (float4*)(out + (size_t)node * DIM);
        o[l16 * 2]     = make_float4(di * acc[0] + b0.x, di * acc[1] + b0.y,
                                     di * acc[2] + b0.z, di * acc[3] + b0.w);
        o[l16 * 2 + 1] = make_float4(di * acc[4] + b1.x, di * acc[5] + b1.y,
                                     di * acc[6] + b1.z, di * acc[7] + b1.w);
    }
}

// ---------------- launch ----------------

extern "C" void kernel_launch(void* const* d_in, const int* in_sizes, int n_in,
                              void* d_out, int out_size, void* d_ws, size_t ws_size,
                              hipStream_t stream) {
    const float* x  = (const float*)d_in[0];
    const int* ei   = (const int*)d_in[1];
    const float* W1 = (const float*)d_in[2];
    const float* b1 = (const float*)d_in[3];
    const float* W2 = (const float*)d_in[4];
    const float* b2 = (const float*)d_in[5];
    const float* W3 = (const float*)d_in[6];
    const float* b3 = (const float*)d_in[7];
    const int* src = ei;
    const int* dst = ei + N_EDGES;
    float* out = (float*)d_out;

    char* w = (char*)d_ws;
    u32* bcnt  = (u32*)w; w += alignUp((size_t)2 * NBUCKET * 4);   // bcnt + bcur (one memset)
    u32* bcur  = bcnt + NBUCKET;
    int* cnt   = (int*)w; w += alignUp((size_t)N_NODES * 4);
    int* base  = (int*)w; w += alignUp((size_t)N_NODES * 4);
    float* dinvb = (float*)w; w += alignUp((size_t)N_NODES * 4);
    u32* epart = (u32*)w; w += alignUp((size_t)N_EDGES * 4);            // bucket-major packed edges
    unsigned short* csr16 = (unsigned short*)w; w += alignUp((size_t)N_EDGES * 2);
    unsigned short* wt = (unsigned short*)w; w += alignUp((size_t)3 * DIM * DIM * 2);
    unsigned short* hbuf  = (unsigned short*)w; w += alignUp((size_t)N_NODES * DIM * 2);
    unsigned short* hbuf2 = (unsigned short*)w; w += alignUp((size_t)N_NODES * DIM * 2);

    hipMemsetAsync(bcnt, 0, (size_t)2 * NBUCKET * 4, stream);

    prep_kernel<<<WT_BLOCKS + P1_BLOCKS, 256, 0, stream>>>(W1, W2, W3, wt, dst, bcnt);
    part_kernel<<<P2_BLOCKS, 256, 0, stream>>>(src, dst, bcnt, bcur, epart);

    // K1: layer-1 GEMM + bucket-CSR build fused (independent, overlaps MFMA)
    gemm_mfma_kernel<<<GEMM_BLOCKS + NBUCKET, 256, 0, stream>>>(x, wt, hbuf, N_NODES,
                                                                bcnt, epart,
                                                                cnt, base, dinvb, csr16);
    // K2: agg(layer1)+relu+b1 fused with layer-2 GEMM (W2)
    aggemm_kernel<<<AGG_BLOCKS, 512, 0, stream>>>((const uint4*)hbuf, wt + DIM * DIM,
                                                  cnt, base, csr16, dinvb,
                                                  (const float4*)b1, hbuf2);
    // K3: agg(layer2)+relu+b2 fused with layer-3 GEMM (W3)
    aggemm_kernel<<<AGG_BLOCKS, 512, 0, stream>>>((const uint4*)hbuf2, wt + 2 * DIM * DIM,
                                                  cnt, base, csr16, dinvb,
                                                  (const float4*)b2, hbuf);
    // K4: final aggregation -> fp32 out (+b3, no relu)
    agg_kernel<<<N_NODES / 4, 256, 0, stream>>>((const uint4*)hbuf, cnt, base, csr16, dinvb,
                                                (const float4*)b3, out);
}

// Round 17
// 240.991 us; speedup vs baseline: 1.0364x; 1.0364x over previous
//
#include <hip/hip_runtime.h>

#define N_NODES 50000
#define N_EDGES 800000
#define DIM 128
#define WT_BLOCKS 192              // 3 * 128*128 / 256
#define GEMM_BLOCKS ((N_NODES + 63) / 64)   // 782 blocks: ~3/CU, small tail
#define NBUCKET ((N_NODES + 255) / 256)   // 196 buckets of 256 nodes (bucket = dst>>8)
#define P1_BLOCKS 200
#define P1_CHUNK 4000              // P1_BLOCKS * P1_CHUNK == N_EDGES
#define P2_BLOCKS 200
#define P2_CHUNK 4000
#define AGG_BLOCKS (N_NODES / 8)   // aggemm: 8 nodes/block, 512 thr

typedef unsigned int u32;
typedef short bf16x8 __attribute__((ext_vector_type(8)));
typedef float f32x4 __attribute__((ext_vector_type(4)));

static inline size_t alignUp(size_t x) { return (x + 255) & ~size_t(255); }

// fp32 -> bf16 round-to-nearest-even (finite values)
__device__ inline unsigned short f2bf(float f) {
    union { float f; u32 u; } v; v.f = f;
    u32 r = v.u + 0x7fffu + ((v.u >> 16) & 1u);
    return (unsigned short)(r >> 16);
}
__device__ inline float bf_lo(u32 u) { return __uint_as_float(u << 16); }
__device__ inline float bf_hi(u32 u) { return __uint_as_float(u & 0xffff0000u); }

__device__ inline void accum8(float acc[8], uint4 r, float w) {
    acc[0] += w * bf_lo(r.x); acc[1] += w * bf_hi(r.x);
    acc[2] += w * bf_lo(r.y); acc[3] += w * bf_hi(r.y);
    acc[4] += w * bf_lo(r.z); acc[5] += w * bf_hi(r.z);
    acc[6] += w * bf_lo(r.w); acc[7] += w * bf_hi(r.w);
}

// ---------------- prep: W->bf16 transpose (blocks [0,WT_BLOCKS)) + bucket counts ----------------
__global__ __launch_bounds__(256) void prep_kernel(const float* __restrict__ W1,
                                                   const float* __restrict__ W2,
                                                   const float* __restrict__ W3,
                                                   unsigned short* __restrict__ Wt,
                                                   const int* __restrict__ dst,
                                                   u32* __restrict__ bcnt) {
    __shared__ u32 hist[NBUCKET];
    int bid = blockIdx.x;
    if (bid < WT_BLOCKS) {
        int m = bid >> 6;                       // which matrix
        int e = (bid & 63) * 256 + threadIdx.x; // element within 128x128
        int n = e >> 7, k = e & 127;
        const float* W = (m == 0) ? W1 : (m == 1) ? W2 : W3;
        Wt[m * DIM * DIM + n * DIM + k] = f2bf(W[(size_t)k * DIM + n]);
        return;
    }
    int b = bid - WT_BLOCKS;
    for (int k = threadIdx.x; k < NBUCKET; k += 256) hist[k] = 0;
    __syncthreads();
    int e0 = b * P1_CHUNK;
    int e1 = min(e0 + P1_CHUNK, N_EDGES);
    for (int i = e0 + threadIdx.x; i < e1; i += 256)
        atomicAdd(&hist[((u32)dst[i]) >> 8], 1u);
    __syncthreads();
    for (int k = threadIdx.x; k < NBUCKET; k += 256)
        if (hist[k]) atomicAdd(&bcnt[k], hist[k]);
}

// ---------------- part: partition edges into bucket-major epart (packed src|dst<<16) ----------
// Bucket bases recomputed locally; bcur is a zero-based reservation counter.
__global__ __launch_bounds__(256) void part_kernel(const int* __restrict__ src,
                                                   const int* __restrict__ dst,
                                                   const u32* __restrict__ bcnt,
                                                   u32* __restrict__ bcur,
                                                   u32* __restrict__ epart) {
    __shared__ u32 ed[P2_CHUNK];
    __shared__ u32 hist[NBUCKET];
    __shared__ u32 cb[NBUCKET];
    __shared__ u32 rk[NBUCKET];
    __shared__ u32 bb[256];
    __shared__ u32 wsum[4];
    int tid = threadIdx.x, lane = tid & 63, wv = tid >> 6;
    u32 c = (tid < NBUCKET) ? bcnt[tid] : 0;
    u32 v = c;
#pragma unroll
    for (int off = 1; off < 64; off <<= 1) {
        u32 u = __shfl_up(v, off, 64);
        if (lane >= off) v += u;
    }
    if (lane == 63) wsum[wv] = v;
    for (int k = tid; k < NBUCKET; k += 256) { hist[k] = 0; rk[k] = 0; }
    __syncthreads();
    u32 wo = 0;
    for (int w = 0; w < wv; w++) wo += wsum[w];
    bb[tid] = wo + v - c;
    __syncthreads();
    int e0 = blockIdx.x * P2_CHUNK;
    int e1 = min(e0 + P2_CHUNK, N_EDGES);
    for (int i = e0 + tid; i < e1; i += 256) {
        u32 s = (u32)src[i], d = (u32)dst[i];
        u32 val = s | (d << 16);
        ed[i - e0] = val;
        atomicAdd(&hist[d >> 8], 1u);
    }
    __syncthreads();
    for (int k = tid; k < NBUCKET; k += 256) {
        u32 ck = hist[k];
        cb[k] = ck ? (bb[k] + atomicAdd(&bcur[k], ck)) : 0u;
    }
    __syncthreads();
    int n = e1 - e0;
    for (int k = tid; k < n; k += 256) {
        u32 val = ed[k];
        u32 bk = val >> 24;                 // (dst>>8), dst fits 16 bits
        u32 r = atomicAdd(&rk[bk], 1u);     // LDS rank
        epart[cb[bk] + r] = val;
    }
}

// ---------------- K1: MFMA GEMM h1 = x(fp32->bf16) @ W1t^T, + bucket-CSR build ----------
#define LDSTRIDE 40
__global__ __launch_bounds__(256) void gemm_mfma_kernel(const float* __restrict__ x,
                                                        const unsigned short* __restrict__ Wt,
                                                        unsigned short* __restrict__ hb,
                                                        int n_rows,
                                                        const u32* __restrict__ bcnt,
                                                        const u32* __restrict__ epart,
                                                        int* __restrict__ cnt,
                                                        int* __restrict__ base,
                                                        float* __restrict__ dinv,
                                                        unsigned short* __restrict__ csr16) {
    __shared__ unsigned short As[64 * LDSTRIDE];
    __shared__ unsigned short Bs[128 * LDSTRIDE];
    if (blockIdx.x >= GEMM_BLOCKS) {
        int B = blockIdx.x - GEMM_BLOCKS;   // bucket id
        u32* hcnt = (u32*)&As[0];           // 256 u32
        u32* pref = hcnt + 256;             // 256 u32
        u32* bbl  = pref + 256;             // 256 u32 (bucket-base scan)
        u32* wsum = bbl + 256;              // 4 u32
        int tid = threadIdx.x, lane = tid & 63, wv = tid >> 6;
        int nb0 = B << 8;
        u32 cb_ = (tid < NBUCKET) ? bcnt[tid] : 0;
        u32 vb = cb_;
#pragma unroll
        for (int off = 1; off < 64; off <<= 1) {
            u32 u = __shfl_up(vb, off, 64);
            if (lane >= off) vb += u;
        }
        if (lane == 63) wsum[wv] = vb;
        hcnt[tid] = 0;
        __syncthreads();
        u32 wob = 0;
        for (int w = 0; w < wv; w++) wob += wsum[w];
        bbl[tid] = wob + vb - cb_;
        __syncthreads();
        u32 ebeg = bbl[B];
        u32 esz  = bcnt[B];
        for (u32 k = tid; k < esz; k += 256)
            atomicAdd(&hcnt[(epart[ebeg + k] >> 16) & 255u], 1u);
        __syncthreads();
        u32 c = hcnt[tid];
        u32 v = c;
#pragma unroll
        for (int off = 1; off < 64; off <<= 1) {
            u32 u = __shfl_up(v, off, 64);
            if (lane >= off) v += u;
        }
        if (lane == 63) wsum[wv] = v;
        __syncthreads();
        u32 wo = 0;
        for (int w = 0; w < wv; w++) wo += wsum[w];
        u32 excl = wo + v - c;
        int node = nb0 + tid;
        if (node < N_NODES) {
            cnt[node]  = (int)c;
            base[node] = (int)(ebeg + excl);
            dinv[node] = rsqrtf((float)(c + 1));
        }
        pref[tid] = excl;
        __syncthreads();
        for (u32 k = tid; k < esz; k += 256) {
            u32 v2 = epart[ebeg + k];
            u32 dl = (v2 >> 16) & 255u;
            u32 r = atomicAdd(&pref[dl], 1u);
            csr16[ebeg + r] = (unsigned short)(v2 & 0xffffu);
        }
        return;
    }
    const int tid = threadIdx.x;
    const int wave = tid >> 6;
    const int lane = tid & 63;
    const int quad = lane >> 4;
    const int l16 = lane & 15;
    const int row0 = blockIdx.x * 64;

    f32x4 acc[8];
#pragma unroll
    for (int nt = 0; nt < 8; nt++) acc[nt] = (f32x4){0.f, 0.f, 0.f, 0.f};

    for (int k0 = 0; k0 < DIM; k0 += 32) {
        {
            int r = tid >> 2;
            int kq = (tid & 3) * 8;
            int gr = row0 + r;
            float4 v0 = make_float4(0.f, 0.f, 0.f, 0.f);
            float4 v1 = make_float4(0.f, 0.f, 0.f, 0.f);
            if (gr < n_rows) {
                v0 = *(const float4*)&x[(size_t)gr * DIM + k0 + kq];
                v1 = *(const float4*)&x[(size_t)gr * DIM + k0 + kq + 4];
            }
            u32 p0 = (u32)f2bf(v0.x) | ((u32)f2bf(v0.y) << 16);
            u32 p1 = (u32)f2bf(v0.z) | ((u32)f2bf(v0.w) << 16);
            u32 p2 = (u32)f2bf(v1.x) | ((u32)f2bf(v1.y) << 16);
            u32 p3 = (u32)f2bf(v1.z) | ((u32)f2bf(v1.w) << 16);
            *(uint4*)&As[r * LDSTRIDE + kq] = make_uint4(p0, p1, p2, p3);
        }
#pragma unroll
        for (int p = 0; p < 2; p++) {
            int nn = p * 64 + (tid >> 2);
            int kk = (tid & 3) * 8;
            *(uint4*)&Bs[nn * LDSTRIDE + kk] = *(const uint4*)&Wt[nn * DIM + k0 + kk];
        }
        __syncthreads();
        const int m0 = wave * 16;
        bf16x8 a = *(const bf16x8*)&As[(m0 + l16) * LDSTRIDE + quad * 8];
#pragma unroll
        for (int nt = 0; nt < 8; nt++) {
            bf16x8 b = *(const bf16x8*)&Bs[(nt * 16 + l16) * LDSTRIDE + quad * 8];
            acc[nt] = __builtin_amdgcn_mfma_f32_16x16x32_bf16(a, b, acc[nt], 0, 0, 0);
        }
        __syncthreads();
    }
    const int m0 = wave * 16;
#pragma unroll
    for (int reg = 0; reg < 4; reg++) {
        int gr = row0 + m0 + quad * 4 + reg;
        if (gr < n_rows) {
#pragma unroll
            for (int nt = 0; nt < 8; nt++)
                hb[(size_t)gr * DIM + nt * 16 + l16] = f2bf(acc[nt][reg]);
        }
    }
}

// ---------------- aggemm: agg(layer i) + GEMM(layer i+1) -----------------------
// ROUND-11/15 VERIFIED FORM (session best, 241.5 us; aggemm 46.9 us, VGPR 28,
// no spill). 512 thr = 8 waves, ONE WAVE PER NODE, 8 nodes/block. W staged in LDS:
// the ds_write+barrier structure forces the W loads to issue EARLY (under the
// gather latency) — register-W (r12-14) loses because the compiler sinks bare W
// loads past the gather phase. Gather depth 2 is the measured optimum (4-deep
// r16: +4.4us from bogus gathers/extra VALU on the 47% deg<16 nodes). LDS 39.4 KB
// -> 4 blocks/CU (32 waves/CU). NO min-wave clamp (r9: (512,8) -> 100 MB spills).
#define FSTR 136   // 272-B rows: 16-B aligned; 2-way bank alias only (free)
__global__ __launch_bounds__(512) void aggemm_kernel(
        const uint4* __restrict__ hb_in,
        const unsigned short* __restrict__ Wt,      // NEXT layer's W^T (bf16)
        const int* __restrict__ cnt,
        const int* __restrict__ basep,
        const unsigned short* __restrict__ csr16,
        const float* __restrict__ dinv,
        const float4* __restrict__ bias4,           // CURRENT layer's bias
        unsigned short* __restrict__ hb_out) {
    __shared__ unsigned short As[16 * FSTR];
    __shared__ unsigned short Bs[128 * FSTR];
    const int tid = threadIdx.x;
    const int wave = tid >> 6;
    const int lane = tid & 63;
    const int g = lane >> 4;
    const int l16 = lane & 15;

    // stage full W (128x128 bf16): 2048 uint4, 4 per thread — issued first
#pragma unroll
    for (int i = 0; i < 4; i++) {
        int idx = i * 512 + tid;
        int n = idx >> 4, k8 = (idx & 15) * 8;
        *(uint4*)&Bs[n * FSTR + k8] = *(const uint4*)&Wt[n * DIM + k8];
    }
    // zero As rows 8..15 (read by MFMA; outputs of those rows never stored)
    {
        u32* az = (u32*)As;
        for (int i = tid; i < (8 * FSTR) / 2; i += 512) az[(8 * FSTR) / 2 + i] = 0;
    }

    // -------- phase A: aggregate node = blk*8 + wave (identical to agg_kernel) ----
    const int node = blockIdx.x * 8 + wave;
    const int deg = cnt[node];
    const float di = dinv[node];
    const int start = basep[node];

    float acc[8];
#pragma unroll
    for (int i = 0; i < 8; i++) acc[i] = 0.f;

    for (int b0 = 0; b0 < deg; b0 += 64) {
        int m = min(64, deg - b0);
        int e = 0; float w = 0.f;
        if (lane < m) {
            e = csr16[start + b0 + lane];
            w = dinv[e];
        }
        for (int j4 = 0; j4 < m; j4 += 8) {   // 2-deep: 2 gathers in flight/lane-group
            int j0 = j4 + g, j1 = j4 + 4 + g;
            int s0 = __shfl(e, j0, 64);  float w0s = __shfl(w, j0, 64);
            int s1 = __shfl(e, j1, 64);  float w1s = __shfl(w, j1, 64);
            uint4 r0 = hb_in[(size_t)s0 * 16 + l16];
            uint4 r1 = hb_in[(size_t)s1 * 16 + l16];
            accum8(acc, r0, w0s);
            accum8(acc, r1, w1s);
        }
    }
    if (g == 0) {   // self-loop (inner weight = dinv[node])
        uint4 r = hb_in[(size_t)node * 16 + l16];
        accum8(acc, r, di);
    }
#pragma unroll
    for (int i = 0; i < 8; i++) {
        acc[i] += __shfl_xor(acc[i], 16, 64);
        acc[i] += __shfl_xor(acc[i], 32, 64);
    }
    if (g == 0) {
        float4 bv0 = bias4[l16 * 2], bv1 = bias4[l16 * 2 + 1];
        float res[8];
        res[0] = di * acc[0] + bv0.x; res[1] = di * acc[1] + bv0.y;
        res[2] = di * acc[2] + bv0.z; res[3] = di * acc[3] + bv0.w;
        res[4] = di * acc[4] + bv1.x; res[5] = di * acc[5] + bv1.y;
        res[6] = di * acc[6] + bv1.z; res[7] = di * acc[7] + bv1.w;
#pragma unroll
        for (int i = 0; i < 8; i++) res[i] = fmaxf(res[i], 0.f);   // fused layers: relu
        u32 p0 = (u32)f2bf(res[0]) | ((u32)f2bf(res[1]) << 16);
        u32 p1 = (u32)f2bf(res[2]) | ((u32)f2bf(res[3]) << 16);
        u32 p2 = (u32)f2bf(res[4]) | ((u32)f2bf(res[5]) << 16);
        u32 p3 = (u32)f2bf(res[6]) | ((u32)f2bf(res[7]) << 16);
        *(uint4*)&As[wave * FSTR + l16 * 8] = make_uint4(p0, p1, p2, p3);
    }
    __syncthreads();

    // -------- phase B: 8x128 @ 128x128 GEMM; wave = N-tile, K=128 in 4 MFMA ----
    const int nt = wave;
    f32x4 gacc = (f32x4){0.f, 0.f, 0.f, 0.f};
#pragma unroll
    for (int ks = 0; ks < 4; ks++) {
        bf16x8 a = *(const bf16x8*)&As[l16 * FSTR + ks * 32 + g * 8];
        bf16x8 b = *(const bf16x8*)&Bs[(nt * 16 + l16) * FSTR + ks * 32 + g * 8];
        gacc = __builtin_amdgcn_mfma_f32_16x16x32_bf16(a, b, gacc, 0, 0, 0);
    }
#pragma unroll
    for (int reg = 0; reg < 4; reg++) {
        int row = g * 4 + reg;          // C layout: row = quad*4+reg, col = l16
        if (row < 8) {
            int gr = blockIdx.x * 8 + row;
            hb_out[(size_t)gr * DIM + nt * 16 + l16] = f2bf(gacc[reg]);
        }
    }
}

// ---------------- final aggregation -> fp32 out ----------------
__global__ __launch_bounds__(256) void agg_kernel(const uint4* __restrict__ hb,
                                                  const int* __restrict__ cnt,
                                                  const int* __restrict__ basep,
                                                  const unsigned short* __restrict__ csr16,
                                                  const float* __restrict__ dinv,
                                                  const float4* __restrict__ bias4,
                                                  float* __restrict__ out) {
    const int wave = threadIdx.x >> 6;
    const int lane = threadIdx.x & 63;
    const int node = blockIdx.x * 4 + wave;
    const int g = lane >> 4;
    const int l16 = lane & 15;

    const int deg = cnt[node];
    const float di = dinv[node];
    const int start = basep[node];

    float acc[8];
#pragma unroll
    for (int i = 0; i < 8; i++) acc[i] = 0.f;

    for (int b0 = 0; b0 < deg; b0 += 64) {
        int m = min(64, deg - b0);
        int e = 0; float w = 0.f;
        if (lane < m) {
            e = csr16[start + b0 + lane];
            w = dinv[e];
        }
        for (int j4 = 0; j4 < m; j4 += 16) {
            int j0 = j4 + g, j1 = j4 + 4 + g, j2 = j4 + 8 + g, j3 = j4 + 12 + g;
            int s0 = __shfl(e, j0, 64);  float w0 = __shfl(w, j0, 64);
            int s1 = __shfl(e, j1, 64);  float w1 = __shfl(w, j1, 64);
            int s2 = __shfl(e, j2, 64);  float w2 = __shfl(w, j2, 64);
            int s3 = __shfl(e, j3, 64);  float w3 = __shfl(w, j3, 64);
            uint4 r0 = hb[(size_t)s0 * 16 + l16];
            uint4 r1 = hb[(size_t)s1 * 16 + l16];
            uint4 r2 = hb[(size_t)s2 * 16 + l16];
            uint4 r3 = hb[(size_t)s3 * 16 + l16];
            accum8(acc, r0, w0);
            accum8(acc, r1, w1);
            accum8(acc, r2, w2);
            accum8(acc, r3, w3);
        }
    }
    if (g == 0) {
        uint4 r = hb[(size_t)node * 16 + l16];
        accum8(acc, r, di);
    }
#pragma unroll
    for (int i = 0; i < 8; i++) {
        acc[i] += __shfl_xor(acc[i], 16, 64);
        acc[i] += __shfl_xor(acc[i], 32, 64);
    }
    if (g == 0) {
        float4 b0 = bias4[l16 * 2], b1 = bias4[l16 * 2 + 1];
        float4* o = (float4*)(out + (size_t)node * DIM);
        o[l16 * 2]     = make_float4(di * acc[0] + b0.x, di * acc[1] + b0.y,
                                     di * acc[2] + b0.z, di * acc[3] + b0.w);
        o[l16 * 2 + 1] = make_float4(di * acc[4] + b1.x, di * acc[5] + b1.y,
                                     di * acc[6] + b1.z, di * acc[7] + b1.w);
    }
}

// ---------------- launch ----------------

extern "C" void kernel_launch(void* const* d_in, const int* in_sizes, int n_in,
                              void* d_out, int out_size, void* d_ws, size_t ws_size,
                              hipStream_t stream) {
    const float* x  = (const float*)d_in[0];
    const int* ei   = (const int*)d_in[1];
    const float* W1 = (const float*)d_in[2];
    const float* b1 = (const float*)d_in[3];
    const float* W2 = (const float*)d_in[4];
    const float* b2 = (const float*)d_in[5];
    const float* W3 = (const float*)d_in[6];
    const float* b3 = (const float*)d_in[7];
    const int* src = ei;
    const int* dst = ei + N_EDGES;
    float* out = (float*)d_out;

    char* w = (char*)d_ws;
    u32* bcnt  = (u32*)w; w += alignUp((size_t)2 * NBUCKET * 4);   // bcnt + bcur (one memset)
    u32* bcur  = bcnt + NBUCKET;
    int* cnt   = (int*)w; w += alignUp((size_t)N_NODES * 4);
    int* base  = (int*)w; w += alignUp((size_t)N_NODES * 4);
    float* dinvb = (float*)w; w += alignUp((size_t)N_NODES * 4);
    u32* epart = (u32*)w; w += alignUp((size_t)N_EDGES * 4);            // bucket-major packed edges
    unsigned short* csr16 = (unsigned short*)w; w += alignUp((size_t)N_EDGES * 2);
    unsigned short* wt = (unsigned short*)w; w += alignUp((size_t)3 * DIM * DIM * 2);
    unsigned short* hbuf  = (unsigned short*)w; w += alignUp((size_t)N_NODES * DIM * 2);
    unsigned short* hbuf2 = (unsigned short*)w; w += alignUp((size_t)N_NODES * DIM * 2);

    hipMemsetAsync(bcnt, 0, (size_t)2 * NBUCKET * 4, stream);

    prep_kernel<<<WT_BLOCKS + P1_BLOCKS, 256, 0, stream>>>(W1, W2, W3, wt, dst, bcnt);
    part_kernel<<<P2_BLOCKS, 256, 0, stream>>>(src, dst, bcnt, bcur, epart);

    // K1: layer-1 GEMM + bucket-CSR build fused (independent, overlaps MFMA)
    gemm_mfma_kernel<<<GEMM_BLOCKS + NBUCKET, 256, 0, stream>>>(x, wt, hbuf, N_NODES,
                                                                bcnt, epart,
                                                                cnt, base, dinvb, csr16);
    // K2: agg(layer1)+relu+b1 fused with layer-2 GEMM (W2)
    aggemm_kernel<<<AGG_BLOCKS, 512, 0, stream>>>((const uint4*)hbuf, wt + DIM * DIM,
                                                  cnt, base, csr16, dinvb,
                                                  (const float4*)b1, hbuf2);
    // K3: agg(layer2)+relu+b2 fused with layer-3 GEMM (W3)
    aggemm_kernel<<<AGG_BLOCKS, 512, 0, stream>>>((const uint4*)hbuf2, wt + 2 * DIM * DIM,
                                                  cnt, base, csr16, dinvb,
                                                  (const float4*)b2, hbuf);
    // K4: final aggregation -> fp32 out (+b3, no relu)
    agg_kernel<<<N_NODES / 4, 256, 0, stream>>>((const uint4*)hbuf, cnt, base, csr16, dinvb,
                                                (const float4*)b3, out);
}